// Round 10
// baseline (314.021 us; speedup 1.0000x reference)
//
#include <hip/hip_runtime.h>

typedef _Float16 f16;
typedef _Float16 f16x8 __attribute__((ext_vector_type(8)));
typedef float f32x4 __attribute__((ext_vector_type(4)));
typedef float f32x16 __attribute__((ext_vector_type(16)));

#define MROWS 64
#define THREADS 512
#define HSTR 264   // f16/row: 528B. 132 words ≡ 4 (mod 32) -> uniform bank spread for 32x32 A-reads

// d_ws layout (bytes)
#define WS_B1EFF 0                      // 256 f32
#define WS_W1H   1024                   // [256][32] f16 (n-major, k<25 valid, rest 0)
#define WS_W2H   (WS_W1H + 16384)       // [256][256] f16  (n-major: W'[n][k] = W[k][n])
#define WS_W3H   (WS_W2H + 131072)
#define WS_W4H   (WS_W3H + 131072)
#define WS_W5H   (WS_W4H + 131072)     // [16][256] f16, cols 9..15 zero
#define WS_END   (WS_W5H + 8192)

// One prep launch: blocks 0..815 convert weights to f16 n-major; block 816 folds the
// constant latent emb[traj] through W1 rows 25..152 into b1eff.  (identical to R8)
__global__ void prep_kernel(const float* __restrict__ emb, const int* __restrict__ traj,
                            const float* __restrict__ W1, const float* __restrict__ b1,
                            const float* __restrict__ W2, const float* __restrict__ W3,
                            const float* __restrict__ W4, const float* __restrict__ W5,
                            float* __restrict__ b1eff,
                            f16* __restrict__ W1h, f16* __restrict__ W2h,
                            f16* __restrict__ W3h, f16* __restrict__ W4h,
                            f16* __restrict__ W5h) {
  if (blockIdx.x == 816) {
    __shared__ float lat[128];
    int t = *traj;
    if (threadIdx.x < 128) lat[threadIdx.x] = emb[t * 128 + threadIdx.x];
    __syncthreads();
    int n = threadIdx.x;
    float s0 = 0.f, s1 = 0.f, s2 = 0.f, s3 = 0.f;
#pragma unroll 4
    for (int d = 0; d < 128; d += 4) {
      s0 = fmaf(lat[d + 0], W1[(25 + d) * 256 + n], s0);
      s1 = fmaf(lat[d + 1], W1[(26 + d) * 256 + n], s1);
      s2 = fmaf(lat[d + 2], W1[(27 + d) * 256 + n], s2);
      s3 = fmaf(lat[d + 3], W1[(28 + d) * 256 + n], s3);
    }
    b1eff[n] = b1[n] + ((s0 + s1) + (s2 + s3));
    return;
  }
  int i = blockIdx.x * 256 + threadIdx.x;
  if (i < 8192) {                       // W1: [153,256] -> [256][32] (tiny; uncoalesced ok)
    int n = i >> 5, k = i & 31;
    W1h[i] = (f16)((k < 25) ? W1[k * 256 + n] : 0.0f);
  } else if (i < 73728) {               // W2: coalesced read, scattered f16 write
    int j = i - 8192; int k = j >> 8, n = j & 255;
    W2h[n * 256 + k] = (f16)W2[j];
  } else if (i < 139264) {
    int j = i - 73728; int k = j >> 8, n = j & 255;
    W3h[n * 256 + k] = (f16)W3[j];
  } else if (i < 204800) {
    int j = i - 139264; int k = j >> 8, n = j & 255;
    W4h[n * 256 + k] = (f16)W4[j];
  } else if (i < 208896) {              // W5: [256,9] -> [16][256], cols 9..15 zero (tiny)
    int j = i - 204800; int n = j >> 8, k = j & 255;
    W5h[j] = (f16)((n < 9) ? W5[k * 9 + n] : 0.0f);
  }
}

// exact-erf GELU in f32 (z^2-form): proven absmax 6.1e-5 path. DO NOT move to f16
// arithmetic (R6: 4.6e-4) and DO NOT repartition the hidden-layer waves to share one
// A-operand across two interleaved MFMA acc chains (R6/R7/R9: nondeterministic fail).
__device__ __forceinline__ float gelu_exact(float z) {
  float s = z * z;
  float q = fmaf(s, -1.8889263e-5f, 2.30872094e-4f);
  q = fmaf(s, q, -0.0023746714834f);
  q = fmaf(s, q, 0.01994711402007f);
  q = fmaf(s, q, -0.13298076013381f);
  q = fmaf(s, q, 0.79788456080287f);
  float t = z * q;          // erf(z/sqrt2)
  float u = 0.5f * z;
  return fmaf(u, t, u);     // 0.5 z (1 + erf)
}

// R10 = R8-green with ONE bitwise-neutral delta: the hidden-layer GELU+f16-convert is
// hoisted ABOVE the read-complete barrier (it touches only private accumulators), so the
// bar1->bar2 critical section shrinks to the 32 ds_write_b16 and the epilogue VALU
// overlaps other waves' LDS/MFMA phase. Same ops, same order -> output bit-identical.
__global__ __launch_bounds__(THREADS, 6) void fused_kernel(
    const float* __restrict__ Fg, const float* __restrict__ Cg,
    const f16* __restrict__ W1h, const f16* __restrict__ W2h,
    const f16* __restrict__ W3h, const f16* __restrict__ W4h,
    const f16* __restrict__ W5h,
    const float* __restrict__ b1eff, const float* __restrict__ b2,
    const float* __restrict__ b3, const float* __restrict__ b4,
    const float* __restrict__ b5, float* __restrict__ outg, int Btot) {
  // sFeat: f16 feats [64][32] for L1; reused as float stage[64][9] in the final epilogue
  __shared__ __align__(16) char sFeat[4096];
  __shared__ __align__(16) f16 hA[64 * HSTR];    // single in-place activation buffer
  __shared__ __align__(16) float o32[64 * 16];
  __shared__ __align__(16) float sR[64 * 9];     // polar rotation stash (phase A -> final)

  const int tid = threadIdx.x;
  const int lane = tid & 63;
  const int wv = tid >> 6;          // 0..7
  const int quad = lane >> 4;       // 16x16 shapes
  const int l15 = lane & 15;
  const int l31 = lane & 31;        // 32x32 shapes
  const int kh = lane >> 5;         // 0/1
  const int row0 = blockIdx.x * MROWS;

  // ---- Phase A: per-row strain features + polar rotation (threads 0..63, one row each)
  if (tid < MROWS) {
    const int grow = row0 + tid;
    float feat[25];
    float Rm[9];
    if (grow < Btot) {
      float Fm[9], Cm[9];
      const float* fp = Fg + grow * 9;
      const float* cp = Cg + grow * 9;
#pragma unroll
      for (int i = 0; i < 9; ++i) Fm[i] = fp[i];
#pragma unroll
      for (int i = 0; i < 9; ++i) Cm[i] = cp[i];
      float G[9];  // F^T F
#pragma unroll
      for (int i = 0; i < 3; ++i)
#pragma unroll
        for (int j = 0; j < 3; ++j)
          G[i * 3 + j] = Fm[i] * Fm[j] + Fm[3 + i] * Fm[3 + j] + Fm[6 + i] * Fm[6 + j];
      float det = Fm[0] * (Fm[4] * Fm[8] - Fm[5] * Fm[7])
                - Fm[1] * (Fm[3] * Fm[8] - Fm[5] * Fm[6])
                + Fm[2] * (Fm[3] * Fm[7] - Fm[4] * Fm[6]);
      // polar Newton: R <- 0.5 (R + R^-T); converges to the SVD rotation U Vh (det F > 0)
#pragma unroll
      for (int i = 0; i < 9; ++i) Rm[i] = Fm[i];
#pragma unroll
      for (int it = 0; it < 5; ++it) {
        float c0 = Rm[4]*Rm[8] - Rm[5]*Rm[7];
        float c1 = Rm[5]*Rm[6] - Rm[3]*Rm[8];
        float c2 = Rm[3]*Rm[7] - Rm[4]*Rm[6];
        float c3 = Rm[2]*Rm[7] - Rm[1]*Rm[8];
        float c4 = Rm[0]*Rm[8] - Rm[2]*Rm[6];
        float c5 = Rm[1]*Rm[6] - Rm[0]*Rm[7];
        float c6 = Rm[1]*Rm[5] - Rm[2]*Rm[4];
        float c7 = Rm[2]*Rm[3] - Rm[0]*Rm[5];
        float c8 = Rm[0]*Rm[4] - Rm[1]*Rm[3];
        float dr = Rm[0]*c0 + Rm[1]*c1 + Rm[2]*c2;
        float hv = 0.5f / dr;
        Rm[0] = 0.5f*Rm[0] + hv*c0; Rm[1] = 0.5f*Rm[1] + hv*c1; Rm[2] = 0.5f*Rm[2] + hv*c2;
        Rm[3] = 0.5f*Rm[3] + hv*c3; Rm[4] = 0.5f*Rm[4] + hv*c4; Rm[5] = 0.5f*Rm[5] + hv*c5;
        Rm[6] = 0.5f*Rm[6] + hv*c6; Rm[7] = 0.5f*Rm[7] + hv*c7; Rm[8] = 0.5f*Rm[8] + hv*c8;
      }
      // S = sym(R^T F); eigenvalues = singular values (descending via trig formula)
      float s00 = Rm[0]*Fm[0] + Rm[3]*Fm[3] + Rm[6]*Fm[6];
      float s11 = Rm[1]*Fm[1] + Rm[4]*Fm[4] + Rm[7]*Fm[7];
      float s22 = Rm[2]*Fm[2] + Rm[5]*Fm[5] + Rm[8]*Fm[8];
      float s01 = 0.5f*((Rm[0]*Fm[1]+Rm[3]*Fm[4]+Rm[6]*Fm[7]) + (Rm[1]*Fm[0]+Rm[4]*Fm[3]+Rm[7]*Fm[6]));
      float s02 = 0.5f*((Rm[0]*Fm[2]+Rm[3]*Fm[5]+Rm[6]*Fm[8]) + (Rm[2]*Fm[0]+Rm[5]*Fm[3]+Rm[8]*Fm[6]));
      float s12 = 0.5f*((Rm[1]*Fm[2]+Rm[4]*Fm[5]+Rm[7]*Fm[8]) + (Rm[2]*Fm[1]+Rm[5]*Fm[4]+Rm[8]*Fm[7]));
      float q  = (s00 + s11 + s22) * (1.0f/3.0f);
      float p1 = s01*s01 + s02*s02 + s12*s12;
      float d0 = s00 - q, d1 = s11 - q, d2 = s22 - q;
      float p2 = d0*d0 + d1*d1 + d2*d2 + 2.0f*p1;
      float p  = sqrtf(p2 * (1.0f/6.0f));
      float e1, e2, e3;
      if (p > 1e-10f) {
        float pi = 1.0f / p;
        float b00 = d0*pi, b11 = d1*pi, b22 = d2*pi;
        float b01 = s01*pi, b02 = s02*pi, b12 = s12*pi;
        float detB = b00*(b11*b22 - b12*b12) - b01*(b01*b22 - b12*b02) + b02*(b01*b12 - b11*b02);
        float r = fminf(fmaxf(0.5f*detB, -1.0f), 1.0f);
        float phi = acosf(r) * (1.0f/3.0f);
        e1 = q + 2.0f * p * cosf(phi);
        e3 = q + 2.0f * p * cosf(phi + 2.0943951023931953f);
        e2 = 3.0f*q - e1 - e3;
      } else { e1 = q; e2 = q; e3 = q; }
      float f00 = fmaxf(Fm[0], 1e-6f);
      feat[0] = e1 - 1.0f; feat[1] = e2 - 1.0f; feat[2] = e3 - 1.0f;
#pragma unroll
      for (int k = 0; k < 9; ++k) feat[3 + k] = G[k];
      feat[3] -= 1.0f; feat[7] -= 1.0f; feat[11] -= 1.0f;
      feat[12] = det - 1.0f;
      feat[13] = logf(det) - 1.0f;
      feat[14] = f00 - 1.0f;
      feat[15] = logf(f00) - 1.0f;
#pragma unroll
      for (int k = 0; k < 9; ++k) feat[16 + k] = Cm[k];
    } else {
#pragma unroll
      for (int k = 0; k < 25; ++k) feat[k] = 0.0f;
#pragma unroll
      for (int k = 0; k < 9; ++k) Rm[k] = 0.0f;
    }
    // stash R for the final epilogue (frees VGPRs across the MLP phase)
#pragma unroll
    for (int k = 0; k < 9; ++k) sR[tid * 9 + k] = Rm[k];
    // store f16 feats, A-frag friendly plain layout [row][32]
#pragma unroll
    for (int c = 0; c < 4; ++c) {
      f16x8 v;
#pragma unroll
      for (int j = 0; j < 8; ++j) {
        int k = c * 8 + j;
        v[j] = (f16)((k < 25) ? feat[k] : 0.0f);
      }
      *(f16x8*)(sFeat + tid * 64 + c * 16) = v;
    }
  }
  __syncthreads();

  // ---- Layer 1 (16x16x32 MFMA, K=32): sFeat -> hA. Wave wv owns cols [wv*32, wv*32+32).
  {
#pragma unroll
    for (int t = 0; t < 2; ++t) {
      const int col = wv * 32 + t * 16 + l15;
      f16x8 bfr = *(const f16x8*)(W1h + col * 32 + quad * 8);
      float bias = b1eff[col];
#pragma unroll
      for (int st = 0; st < 4; ++st) {
        const int arow = st * 16 + l15;
        f16x8 a = *(const f16x8*)(sFeat + arow * 64 + quad * 16);
        f32x4 acc = (f32x4){bias, bias, bias, bias};
        acc = __builtin_amdgcn_mfma_f32_16x16x32_f16(a, bfr, acc, 0, 0, 0);
#pragma unroll
        for (int r = 0; r < 4; ++r) {
          const int orow = st * 16 + quad * 4 + r;
          hA[orow * HSTR + col] = (f16)gelu_exact(acc[r]);
        }
      }
    }
  }
  __syncthreads();

  // ---- Hidden layers 2..4 (32x32x16 MFMA), IN-PLACE in hA (R8 partition: wave wv owns
  //   cols [wv*32,+32), reads both 32-row tiles; acc chains NOT interleaved — see note).
  //   [reads+MFMA+gelu->regs] bar1 [writes only] bar2.
  const f16* Whs[3] = {W2h, W3h, W4h};
  const float* bgs[3] = {b2, b3, b4};
  const int col32 = wv * 32 + l31;
#pragma unroll 1
  for (int L = 0; L < 3; ++L) {
    const f16* Wh = Whs[L];
    const float bias = bgs[L][col32];
    f32x16 acc0, acc1;
#pragma unroll
    for (int r = 0; r < 16; ++r) { acc0[r] = bias; acc1[r] = bias; }   // bias folded into init
#pragma unroll
    for (int q = 0; q < 4; ++q) {                 // B in quarters: 16 VGPRs live, not 64
      f16x8 bq[4];
#pragma unroll
      for (int j = 0; j < 4; ++j)
        bq[j] = *(const f16x8*)(Wh + col32 * 256 + (q * 4 + j) * 16 + kh * 8);
#pragma unroll
      for (int j = 0; j < 4; ++j) {
        f16x8 a0 = *(const f16x8*)(hA + l31 * HSTR + (q * 4 + j) * 16 + kh * 8);
        acc0 = __builtin_amdgcn_mfma_f32_32x32x16_f16(a0, bq[j], acc0, 0, 0, 0);
      }
#pragma unroll
      for (int j = 0; j < 4; ++j) {
        f16x8 a1 = *(const f16x8*)(hA + (32 + l31) * HSTR + (q * 4 + j) * 16 + kh * 8);
        acc1 = __builtin_amdgcn_mfma_f32_32x32x16_f16(a1, bq[j], acc1, 0, 0, 0);
      }
    }
    // GELU + f16 convert into PRIVATE regs before the barrier (overlaps other waves'
    // LDS/MFMA phase; bar1->bar2 shrinks to the stores). Bitwise-identical to R8.
    f16 hv0[16], hv1[16];
#pragma unroll
    for (int r = 0; r < 16; ++r) {
      hv0[r] = (f16)gelu_exact(acc0[r]);
      hv1[r] = (f16)gelu_exact(acc1[r]);
    }
    __syncthreads();                              // all reads of hA done
#pragma unroll
    for (int r = 0; r < 16; ++r) {
      const int orow = (r & 3) + 8 * (r >> 2) + 4 * kh;
      hA[orow * HSTR + col32] = hv0[r];
      hA[(32 + orow) * HSTR + col32] = hv1[r];
    }
    __syncthreads();                              // strip writes visible to all
  }

  // ---- Layer 5 (16x16x32, N=16, 9 valid): waves 0..3, wave wv does rows [wv*16, +16); reads hA
  if (wv < 4) {
    f16x8 bf5[8];
#pragma unroll
    for (int s = 0; s < 8; ++s)
      bf5[s] = *(const f16x8*)(W5h + l15 * 256 + s * 32 + quad * 8);
    const int arow = wv * 16 + l15;
    float bv = (l15 < 9) ? b5[l15] : 0.0f;
    f32x4 acc = (f32x4){bv, bv, bv, bv};
#pragma unroll
    for (int s = 0; s < 8; ++s) {
      f16x8 a = *(const f16x8*)(hA + arow * HSTR + s * 32 + quad * 8);
      acc = __builtin_amdgcn_mfma_f32_16x16x32_f16(a, bf5[s], acc, 0, 0, 0);
    }
#pragma unroll
    for (int r = 0; r < 4; ++r) {
      const int orow = wv * 16 + quad * 4 + r;
      o32[orow * 16 + l15] = acc[r];
    }
  }
  __syncthreads();

  // ---- Final per-row: cauchy = R * sym(x) * F^T ; stage in sFeat then coalesced store
  float* stage = (float*)sFeat;
  if (tid < MROWS && row0 + tid < Btot) {
    const float* x = o32 + tid * 16;
    const float* fp = Fg + (row0 + tid) * 9;   // F re-read (L2-hot); R from LDS stash
    float Fm[9], Rm[9];
#pragma unroll
    for (int i = 0; i < 9; ++i) Fm[i] = fp[i];
#pragma unroll
    for (int i = 0; i < 9; ++i) Rm[i] = sR[tid * 9 + i];
    float y[9];
    y[0] = x[0]; y[4] = x[4]; y[8] = x[8];
    y[1] = 0.5f * (x[1] + x[3]); y[3] = y[1];
    y[2] = 0.5f * (x[2] + x[6]); y[6] = y[2];
    y[5] = 0.5f * (x[5] + x[7]); y[7] = y[5];
    float P[9];
#pragma unroll
    for (int i = 0; i < 3; ++i)
#pragma unroll
      for (int j = 0; j < 3; ++j)
        P[i*3+j] = Rm[i*3]*y[j] + Rm[i*3+1]*y[3+j] + Rm[i*3+2]*y[6+j];
#pragma unroll
    for (int i = 0; i < 3; ++i)
#pragma unroll
      for (int j = 0; j < 3; ++j)
        stage[tid*9 + i*3 + j] = P[i*3]*Fm[j*3] + P[i*3+1]*Fm[j*3+1] + P[i*3+2]*Fm[j*3+2];
  }
  __syncthreads();
  for (int i = tid; i < MROWS * 9; i += THREADS) {
    int gi = row0 * 9 + i;
    if (gi < Btot * 9) outg[gi] = stage[i];
  }
}

extern "C" void kernel_launch(void* const* d_in, const int* in_sizes, int n_in,
                              void* d_out, int out_size, void* d_ws, size_t ws_size,
                              hipStream_t stream) {
  const float* Fg  = (const float*)d_in[0];
  const float* Cg  = (const float*)d_in[1];
  const float* emb = (const float*)d_in[2];
  const int*   trj = (const int*)d_in[3];
  const float* W1  = (const float*)d_in[4];
  const float* b1  = (const float*)d_in[5];
  const float* W2  = (const float*)d_in[6];
  const float* b2  = (const float*)d_in[7];
  const float* W3  = (const float*)d_in[8];
  const float* b3  = (const float*)d_in[9];
  const float* W4  = (const float*)d_in[10];
  const float* b4  = (const float*)d_in[11];
  const float* W5  = (const float*)d_in[12];
  const float* b5  = (const float*)d_in[13];
  float* outg = (float*)d_out;
  const int Btot = in_sizes[0] / 9;

  char* ws = (char*)d_ws;
  float* b1eff = (float*)(ws + WS_B1EFF);
  f16* W1h = (f16*)(ws + WS_W1H);
  f16* W2h = (f16*)(ws + WS_W2H);
  f16* W3h = (f16*)(ws + WS_W3H);
  f16* W4h = (f16*)(ws + WS_W4H);
  f16* W5h = (f16*)(ws + WS_W5H);

  prep_kernel<<<817, 256, 0, stream>>>(emb, trj, W1, b1, W2, W3, W4, W5,
                                       b1eff, W1h, W2h, W3h, W4h, W5h);
  const int grid = (Btot + MROWS - 1) / MROWS;
  fused_kernel<<<grid, THREADS, 0, stream>>>(Fg, Cg, W1h, W2h, W3h, W4h, W5h,
                                             b1eff, b2, b3, b4, b5, outg, Btot);
}

// Round 11
// 260.240 us; speedup vs baseline: 1.2067x; 1.2067x over previous
//
#include <hip/hip_runtime.h>

typedef _Float16 f16;
typedef _Float16 f16x8 __attribute__((ext_vector_type(8)));
typedef float f32x4 __attribute__((ext_vector_type(4)));
typedef float f32x16 __attribute__((ext_vector_type(16)));

#define MROWS 128
#define THREADS 512
#define HSTR 264   // f16/row: 528B, 16B-aligned rows (HSTR must be mult. of 8)

// d_ws layout (bytes)
#define WS_B1EFF 0                      // 256 f32
#define WS_W1H   1024                   // [256][32] f16 (n-major, k<25 valid, rest 0)
#define WS_W2H   (WS_W1H + 16384)       // [256][256] f16  (n-major: W'[n][k] = W[k][n])
#define WS_W3H   (WS_W2H + 131072)
#define WS_W4H   (WS_W3H + 131072)
#define WS_W5H   (WS_W4H + 131072)     // [16][256] f16, cols 9..15 zero
#define WS_END   (WS_W5H + 8192)

// prep identical to R8-green.
__global__ void prep_kernel(const float* __restrict__ emb, const int* __restrict__ traj,
                            const float* __restrict__ W1, const float* __restrict__ b1,
                            const float* __restrict__ W2, const float* __restrict__ W3,
                            const float* __restrict__ W4, const float* __restrict__ W5,
                            float* __restrict__ b1eff,
                            f16* __restrict__ W1h, f16* __restrict__ W2h,
                            f16* __restrict__ W3h, f16* __restrict__ W4h,
                            f16* __restrict__ W5h) {
  if (blockIdx.x == 816) {
    __shared__ float lat[128];
    int t = *traj;
    if (threadIdx.x < 128) lat[threadIdx.x] = emb[t * 128 + threadIdx.x];
    __syncthreads();
    int n = threadIdx.x;
    float s0 = 0.f, s1 = 0.f, s2 = 0.f, s3 = 0.f;
#pragma unroll 4
    for (int d = 0; d < 128; d += 4) {
      s0 = fmaf(lat[d + 0], W1[(25 + d) * 256 + n], s0);
      s1 = fmaf(lat[d + 1], W1[(26 + d) * 256 + n], s1);
      s2 = fmaf(lat[d + 2], W1[(27 + d) * 256 + n], s2);
      s3 = fmaf(lat[d + 3], W1[(28 + d) * 256 + n], s3);
    }
    b1eff[n] = b1[n] + ((s0 + s1) + (s2 + s3));
    return;
  }
  int i = blockIdx.x * 256 + threadIdx.x;
  if (i < 8192) {
    int n = i >> 5, k = i & 31;
    W1h[i] = (f16)((k < 25) ? W1[k * 256 + n] : 0.0f);
  } else if (i < 73728) {
    int j = i - 8192; int k = j >> 8, n = j & 255;
    W2h[n * 256 + k] = (f16)W2[j];
  } else if (i < 139264) {
    int j = i - 73728; int k = j >> 8, n = j & 255;
    W3h[n * 256 + k] = (f16)W3[j];
  } else if (i < 204800) {
    int j = i - 139264; int k = j >> 8, n = j & 255;
    W4h[n * 256 + k] = (f16)W4[j];
  } else if (i < 208896) {
    int j = i - 204800; int n = j >> 8, k = j & 255;
    W5h[j] = (f16)((n < 9) ? W5[k * 9 + n] : 0.0f);
  }
}

// exact-erf GELU in f32 (z^2-form): proven absmax 6.1e-5 path. DO NOT move to f16
// arithmetic (R6: 4.6e-4) and DO NOT interleave two MFMA acc chains off one A register
// (R6/R7/R9: nondeterministic fail). Sequential per-tile loops sharing B regs are proven.
__device__ __forceinline__ float gelu_exact(float z) {
  float s = z * z;
  float q = fmaf(s, -1.8889263e-5f, 2.30872094e-4f);
  q = fmaf(s, q, -0.0023746714834f);
  q = fmaf(s, q, 0.01994711402007f);
  q = fmaf(s, q, -0.13298076013381f);
  q = fmaf(s, q, 0.79788456080287f);
  float t = z * q;          // erf(z/sqrt2)
  float u = 0.5f * z;
  return fmaf(u, t, u);     // 0.5 z (1 + erf)
}

// R11 = R10 structure scaled to 128-row blocks (4 sequential row-tiles per wave,
// R8-proven loop shape). Per-element summation order unchanged -> bitwise-identical.
// LDS: hA 67.6KB + (sFeat|o32 overlay) 8KB + sR 4.6KB ~= 80.4KB -> 2 blocks/CU.
__global__ __launch_bounds__(THREADS, 4) void fused_kernel(
    const float* __restrict__ Fg, const float* __restrict__ Cg,
    const f16* __restrict__ W1h, const f16* __restrict__ W2h,
    const f16* __restrict__ W3h, const f16* __restrict__ W4h,
    const f16* __restrict__ W5h,
    const float* __restrict__ b1eff, const float* __restrict__ b2,
    const float* __restrict__ b3, const float* __restrict__ b4,
    const float* __restrict__ b5, float* __restrict__ outg, int Btot) {
  __shared__ __align__(16) f16 hA[MROWS * HSTR];   // activations; reused as float stage at end
  __shared__ __align__(16) char uFO[MROWS * 64];   // sFeat f16[128][32] early; o32 f32[128][16] late
  __shared__ __align__(16) float sR[MROWS * 9];    // polar rotation stash (phase A -> final)

  const int tid = threadIdx.x;
  const int lane = tid & 63;
  const int wv = tid >> 6;          // 0..7
  const int quad = lane >> 4;       // 16x16 shapes
  const int l15 = lane & 15;
  const int l31 = lane & 31;        // 32x32 shapes
  const int kh = lane >> 5;         // 0/1
  const int row0 = blockIdx.x * MROWS;

  // ---- Phase A: per-row strain features + polar rotation (threads 0..127, one row each)
  if (tid < MROWS) {
    const int grow = row0 + tid;
    float feat[25];
    float Rm[9];
    if (grow < Btot) {
      float Fm[9], Cm[9];
      const float* fp = Fg + grow * 9;
      const float* cp = Cg + grow * 9;
#pragma unroll
      for (int i = 0; i < 9; ++i) Fm[i] = fp[i];
#pragma unroll
      for (int i = 0; i < 9; ++i) Cm[i] = cp[i];
      float G[9];  // F^T F
#pragma unroll
      for (int i = 0; i < 3; ++i)
#pragma unroll
        for (int j = 0; j < 3; ++j)
          G[i * 3 + j] = Fm[i] * Fm[j] + Fm[3 + i] * Fm[3 + j] + Fm[6 + i] * Fm[6 + j];
      float det = Fm[0] * (Fm[4] * Fm[8] - Fm[5] * Fm[7])
                - Fm[1] * (Fm[3] * Fm[8] - Fm[5] * Fm[6])
                + Fm[2] * (Fm[3] * Fm[7] - Fm[4] * Fm[6]);
      // polar Newton: R <- 0.5 (R + R^-T); converges to the SVD rotation U Vh (det F > 0)
#pragma unroll
      for (int i = 0; i < 9; ++i) Rm[i] = Fm[i];
#pragma unroll
      for (int it = 0; it < 5; ++it) {
        float c0 = Rm[4]*Rm[8] - Rm[5]*Rm[7];
        float c1 = Rm[5]*Rm[6] - Rm[3]*Rm[8];
        float c2 = Rm[3]*Rm[7] - Rm[4]*Rm[6];
        float c3 = Rm[2]*Rm[7] - Rm[1]*Rm[8];
        float c4 = Rm[0]*Rm[8] - Rm[2]*Rm[6];
        float c5 = Rm[1]*Rm[6] - Rm[0]*Rm[7];
        float c6 = Rm[1]*Rm[5] - Rm[2]*Rm[4];
        float c7 = Rm[2]*Rm[3] - Rm[0]*Rm[5];
        float c8 = Rm[0]*Rm[4] - Rm[1]*Rm[3];
        float dr = Rm[0]*c0 + Rm[1]*c1 + Rm[2]*c2;
        float hv = 0.5f / dr;
        Rm[0] = 0.5f*Rm[0] + hv*c0; Rm[1] = 0.5f*Rm[1] + hv*c1; Rm[2] = 0.5f*Rm[2] + hv*c2;
        Rm[3] = 0.5f*Rm[3] + hv*c3; Rm[4] = 0.5f*Rm[4] + hv*c4; Rm[5] = 0.5f*Rm[5] + hv*c5;
        Rm[6] = 0.5f*Rm[6] + hv*c6; Rm[7] = 0.5f*Rm[7] + hv*c7; Rm[8] = 0.5f*Rm[8] + hv*c8;
      }
      // S = sym(R^T F); eigenvalues = singular values (descending via trig formula)
      float s00 = Rm[0]*Fm[0] + Rm[3]*Fm[3] + Rm[6]*Fm[6];
      float s11 = Rm[1]*Fm[1] + Rm[4]*Fm[4] + Rm[7]*Fm[7];
      float s22 = Rm[2]*Fm[2] + Rm[5]*Fm[5] + Rm[8]*Fm[8];
      float s01 = 0.5f*((Rm[0]*Fm[1]+Rm[3]*Fm[4]+Rm[6]*Fm[7]) + (Rm[1]*Fm[0]+Rm[4]*Fm[3]+Rm[7]*Fm[6]));
      float s02 = 0.5f*((Rm[0]*Fm[2]+Rm[3]*Fm[5]+Rm[6]*Fm[8]) + (Rm[2]*Fm[0]+Rm[5]*Fm[3]+Rm[8]*Fm[6]));
      float s12 = 0.5f*((Rm[1]*Fm[2]+Rm[4]*Fm[5]+Rm[7]*Fm[8]) + (Rm[2]*Fm[1]+Rm[5]*Fm[4]+Rm[8]*Fm[7]));
      float q  = (s00 + s11 + s22) * (1.0f/3.0f);
      float p1 = s01*s01 + s02*s02 + s12*s12;
      float d0 = s00 - q, d1 = s11 - q, d2 = s22 - q;
      float p2 = d0*d0 + d1*d1 + d2*d2 + 2.0f*p1;
      float p  = sqrtf(p2 * (1.0f/6.0f));
      float e1, e2, e3;
      if (p > 1e-10f) {
        float pi = 1.0f / p;
        float b00 = d0*pi, b11 = d1*pi, b22 = d2*pi;
        float b01 = s01*pi, b02 = s02*pi, b12 = s12*pi;
        float detB = b00*(b11*b22 - b12*b12) - b01*(b01*b22 - b12*b02) + b02*(b01*b12 - b11*b02);
        float r = fminf(fmaxf(0.5f*detB, -1.0f), 1.0f);
        float phi = acosf(r) * (1.0f/3.0f);
        e1 = q + 2.0f * p * cosf(phi);
        e3 = q + 2.0f * p * cosf(phi + 2.0943951023931953f);
        e2 = 3.0f*q - e1 - e3;
      } else { e1 = q; e2 = q; e3 = q; }
      float f00 = fmaxf(Fm[0], 1e-6f);
      feat[0] = e1 - 1.0f; feat[1] = e2 - 1.0f; feat[2] = e3 - 1.0f;
#pragma unroll
      for (int k = 0; k < 9; ++k) feat[3 + k] = G[k];
      feat[3] -= 1.0f; feat[7] -= 1.0f; feat[11] -= 1.0f;
      feat[12] = det - 1.0f;
      feat[13] = logf(det) - 1.0f;
      feat[14] = f00 - 1.0f;
      feat[15] = logf(f00) - 1.0f;
#pragma unroll
      for (int k = 0; k < 9; ++k) feat[16 + k] = Cm[k];
    } else {
#pragma unroll
      for (int k = 0; k < 25; ++k) feat[k] = 0.0f;
#pragma unroll
      for (int k = 0; k < 9; ++k) Rm[k] = 0.0f;
    }
#pragma unroll
    for (int k = 0; k < 9; ++k) sR[tid * 9 + k] = Rm[k];
    // store f16 feats, A-frag friendly plain layout [row][32] into uFO
#pragma unroll
    for (int c = 0; c < 4; ++c) {
      f16x8 v;
#pragma unroll
      for (int j = 0; j < 8; ++j) {
        int k = c * 8 + j;
        v[j] = (f16)((k < 25) ? feat[k] : 0.0f);
      }
      *(f16x8*)(uFO + tid * 64 + c * 16) = v;
    }
  }
  __syncthreads();

  // ---- Layer 1 (16x16x32 MFMA, K=32): uFO(feats) -> hA. Wave wv owns cols [wv*32,+32).
  {
#pragma unroll
    for (int t = 0; t < 2; ++t) {
      const int col = wv * 32 + t * 16 + l15;
      f16x8 bfr = *(const f16x8*)(W1h + col * 32 + quad * 8);
      float bias = b1eff[col];
#pragma unroll
      for (int st = 0; st < 8; ++st) {             // 8 row-subtiles of 16
        const int arow = st * 16 + l15;
        f16x8 a = *(const f16x8*)(uFO + arow * 64 + quad * 16);
        f32x4 acc = (f32x4){bias, bias, bias, bias};
        acc = __builtin_amdgcn_mfma_f32_16x16x32_f16(a, bfr, acc, 0, 0, 0);
#pragma unroll
        for (int r = 0; r < 4; ++r) {
          const int orow = st * 16 + quad * 4 + r;
          hA[orow * HSTR + col] = (f16)gelu_exact(acc[r]);
        }
      }
    }
  }
  __syncthreads();

  // ---- Hidden layers 2..4 (32x32x16 MFMA), IN-PLACE in hA. Wave wv owns cols
  // [wv*32,+32), 4 sequential row-tiles (R8-proven loop shape, acc chains NOT interleaved).
  // [reads+MFMA+gelu->regs] bar1 [writes only] bar2.
  const f16* Whs[3] = {W2h, W3h, W4h};
  const float* bgs[3] = {b2, b3, b4};
  const int col32 = wv * 32 + l31;
#pragma unroll 1
  for (int L = 0; L < 3; ++L) {
    const f16* Wh = Whs[L];
    const float bias = bgs[L][col32];
    f32x16 acc0, acc1, acc2, acc3;
#pragma unroll
    for (int r = 0; r < 16; ++r) { acc0[r] = bias; acc1[r] = bias; acc2[r] = bias; acc3[r] = bias; }
#pragma unroll
    for (int q = 0; q < 4; ++q) {                 // B in quarters: 16 VGPRs live
      f16x8 bq[4];
#pragma unroll
      for (int j = 0; j < 4; ++j)
        bq[j] = *(const f16x8*)(Wh + col32 * 256 + (q * 4 + j) * 16 + kh * 8);
#pragma unroll
      for (int j = 0; j < 4; ++j) {
        f16x8 a = *(const f16x8*)(hA + l31 * HSTR + (q * 4 + j) * 16 + kh * 8);
        acc0 = __builtin_amdgcn_mfma_f32_32x32x16_f16(a, bq[j], acc0, 0, 0, 0);
      }
#pragma unroll
      for (int j = 0; j < 4; ++j) {
        f16x8 a = *(const f16x8*)(hA + (32 + l31) * HSTR + (q * 4 + j) * 16 + kh * 8);
        acc1 = __builtin_amdgcn_mfma_f32_32x32x16_f16(a, bq[j], acc1, 0, 0, 0);
      }
#pragma unroll
      for (int j = 0; j < 4; ++j) {
        f16x8 a = *(const f16x8*)(hA + (64 + l31) * HSTR + (q * 4 + j) * 16 + kh * 8);
        acc2 = __builtin_amdgcn_mfma_f32_32x32x16_f16(a, bq[j], acc2, 0, 0, 0);
      }
#pragma unroll
      for (int j = 0; j < 4; ++j) {
        f16x8 a = *(const f16x8*)(hA + (96 + l31) * HSTR + (q * 4 + j) * 16 + kh * 8);
        acc3 = __builtin_amdgcn_mfma_f32_32x32x16_f16(a, bq[j], acc3, 0, 0, 0);
      }
    }
    // GELU + f16 convert into PRIVATE regs before the barrier (R10-proven hoist)
    f16 hv0[16], hv1[16], hv2[16], hv3[16];
#pragma unroll
    for (int r = 0; r < 16; ++r) {
      hv0[r] = (f16)gelu_exact(acc0[r]);
      hv1[r] = (f16)gelu_exact(acc1[r]);
      hv2[r] = (f16)gelu_exact(acc2[r]);
      hv3[r] = (f16)gelu_exact(acc3[r]);
    }
    __syncthreads();                              // all reads of hA done
#pragma unroll
    for (int r = 0; r < 16; ++r) {
      const int orow = (r & 3) + 8 * (r >> 2) + 4 * kh;
      hA[orow * HSTR + col32]        = hv0[r];
      hA[(32 + orow) * HSTR + col32] = hv1[r];
      hA[(64 + orow) * HSTR + col32] = hv2[r];
      hA[(96 + orow) * HSTR + col32] = hv3[r];
    }
    __syncthreads();                              // strip writes visible to all
  }

  // ---- Layer 5 (16x16x32, N=16, 9 valid): all 8 waves, wave wv rows [wv*16,+16); reads hA
  {
    float* o32 = (float*)uFO;                     // overlay: feats dead after L1
    f16x8 bf5[8];
#pragma unroll
    for (int s = 0; s < 8; ++s)
      bf5[s] = *(const f16x8*)(W5h + l15 * 256 + s * 32 + quad * 8);
    const int arow = wv * 16 + l15;
    float bv = (l15 < 9) ? b5[l15] : 0.0f;
    f32x4 acc = (f32x4){bv, bv, bv, bv};
#pragma unroll
    for (int s = 0; s < 8; ++s) {
      f16x8 a = *(const f16x8*)(hA + arow * HSTR + s * 32 + quad * 8);
      acc = __builtin_amdgcn_mfma_f32_16x16x32_f16(a, bf5[s], acc, 0, 0, 0);
    }
#pragma unroll
    for (int r = 0; r < 4; ++r) {
      const int orow = wv * 16 + quad * 4 + r;
      o32[orow * 16 + l15] = acc[r];
    }
  }
  __syncthreads();

  // ---- Final per-row: cauchy = R * sym(x) * F^T ; stage into hA region (free after L5)
  float* stage = (float*)hA;
  const float* o32c = (const float*)uFO;
  if (tid < MROWS && row0 + tid < Btot) {
    const float* x = o32c + tid * 16;
    const float* fp = Fg + (row0 + tid) * 9;   // F re-read (L2-hot); R from LDS stash
    float Fm[9], Rm[9];
#pragma unroll
    for (int i = 0; i < 9; ++i) Fm[i] = fp[i];
#pragma unroll
    for (int i = 0; i < 9; ++i) Rm[i] = sR[tid * 9 + i];
    float y[9];
    y[0] = x[0]; y[4] = x[4]; y[8] = x[8];
    y[1] = 0.5f * (x[1] + x[3]); y[3] = y[1];
    y[2] = 0.5f * (x[2] + x[6]); y[6] = y[2];
    y[5] = 0.5f * (x[5] + x[7]); y[7] = y[5];
    float P[9];
#pragma unroll
    for (int i = 0; i < 3; ++i)
#pragma unroll
      for (int j = 0; j < 3; ++j)
        P[i*3+j] = Rm[i*3]*y[j] + Rm[i*3+1]*y[3+j] + Rm[i*3+2]*y[6+j];
#pragma unroll
    for (int i = 0; i < 3; ++i)
#pragma unroll
      for (int j = 0; j < 3; ++j)
        stage[tid*9 + i*3 + j] = P[i*3]*Fm[j*3] + P[i*3+1]*Fm[j*3+1] + P[i*3+2]*Fm[j*3+2];
  }
  __syncthreads();
  for (int i = tid; i < MROWS * 9; i += THREADS) {
    int gi = row0 * 9 + i;
    if (gi < Btot * 9) outg[gi] = stage[i];
  }
}

extern "C" void kernel_launch(void* const* d_in, const int* in_sizes, int n_in,
                              void* d_out, int out_size, void* d_ws, size_t ws_size,
                              hipStream_t stream) {
  const float* Fg  = (const float*)d_in[0];
  const float* Cg  = (const float*)d_in[1];
  const float* emb = (const float*)d_in[2];
  const int*   trj = (const int*)d_in[3];
  const float* W1  = (const float*)d_in[4];
  const float* b1  = (const float*)d_in[5];
  const float* W2  = (const float*)d_in[6];
  const float* b2  = (const float*)d_in[7];
  const float* W3  = (const float*)d_in[8];
  const float* b3  = (const float*)d_in[9];
  const float* W4  = (const float*)d_in[10];
  const float* b4  = (const float*)d_in[11];
  const float* W5  = (const float*)d_in[12];
  const float* b5  = (const float*)d_in[13];
  float* outg = (float*)d_out;
  const int Btot = in_sizes[0] / 9;

  char* ws = (char*)d_ws;
  float* b1eff = (float*)(ws + WS_B1EFF);
  f16* W1h = (f16*)(ws + WS_W1H);
  f16* W2h = (f16*)(ws + WS_W2H);
  f16* W3h = (f16*)(ws + WS_W3H);
  f16* W4h = (f16*)(ws + WS_W4H);
  f16* W5h = (f16*)(ws + WS_W5H);

  prep_kernel<<<817, 256, 0, stream>>>(emb, trj, W1, b1, W2, W3, W4, W5,
                                       b1eff, W1h, W2h, W3h, W4h, W5h);
  const int grid = (Btot + MROWS - 1) / MROWS;
  fused_kernel<<<grid, THREADS, 0, stream>>>(Fg, Cg, W1h, W2h, W3h, W4h, W5h,
                                             b1eff, b2, b3, b4, b5, outg, Btot);
}